// Round 1
// baseline (88.603 us; speedup 1.0000x reference)
//
#include <hip/hip_runtime.h>
#include <cstdint>
#include <cstddef>

// ============================================================================
// ProposalTargetLayer (MSDN / Faster-RCNN), gfx950. Round 8.
// Round 7 + k_prep LDS-pipe fix: the inner 64-iteration loop issued TWO
// broadcast LDS reads per gt (b128 box + b32 area) and was LDS-issue-bound
// (~17.8 cy/iter LDS vs 34 cy/iter VALU per wave; ~11.3 us vs 5.4 us
// chip-wide). The gt area is now recomputed inline (5 VALU ops on the
// half-idle VALU pipe) -- bit-identical expression to the staged value, so
// all discrete decisions are unchanged. sga[] removed from k_prep.
//
// Pipeline: k_prep -> k_select -> k_final   (3 dispatches)
//  - k_prep: TWO threads per roi (gt-half split h=0/1). Each thread: 64 IoU
//    tests (divide-free exact fg test) + ONE threefry hash (its channel);
//    partial fg merged via LDS; h writes vb row (h*kB+b). 1520 blocks ->
//    ~6 waves/SIMD.
//  - k_select: 1024 threads/block: pass1 hist-on-load, scan -> threshold
//    bin, pass2 filtered candidates, exact rank. 32 blocks.
//  - k_final: one wave per output roi; butterfly argmax on
//    (iou_bits<<7)|(127-g) == reference first-win argmax.
// Bit-exact discrete decisions (verified rounds 1-7, absmax 0.0):
//  * fg: round(inter/denom)>=0.5 <=> fmaf(-.5,den,inter) >= (-2^-26)*den
//  * bg = !fg;  top_k tie-break via (valbits<<32)|(~idx) exact ranking;
//  * threefry partitionable split/uniform identical to jax.random;
//  * argmax: max over (iou_bits, lower-g-wins) == first strict max.
// ============================================================================

#define THREEFRY_PARTITIONABLE 1

constexpr int kB = 16;
constexpr int kN = 12000;
constexpr int kG = 128;
constexpr int kM = kN + kG;   // 12128
constexpr int kM4 = kM / 4;   // 3032 (exact)
constexpr int kR = 256;
constexpr int kFgQuota = 64;
constexpr unsigned kSeedHi = 0u;
constexpr unsigned kSeedLo = 42u;   // jax.random.key(42)

__device__ __forceinline__ int imin(int a, int b) { return a < b ? a : b; }
__device__ __forceinline__ int imax(int a, int b) { return a > b ? a : b; }

__device__ __forceinline__ unsigned rotl32(unsigned v, int d) {
  return (v << d) | (v >> (32 - d));
}

// Threefry-2x32, 20 rounds, exactly as in jax/_src/prng.py.
__device__ __forceinline__ void tf2x32(unsigned k0, unsigned k1,
                                       unsigned x0, unsigned x1,
                                       unsigned& o0, unsigned& o1) {
  const unsigned k2 = k0 ^ k1 ^ 0x1BD11BDAu;
  x0 += k0; x1 += k1;
#define TF_R(d) x0 += x1; x1 = rotl32(x1, d); x1 ^= x0;
  TF_R(13) TF_R(15) TF_R(26) TF_R(6)
  x0 += k1; x1 += k2 + 1u;
  TF_R(17) TF_R(29) TF_R(16) TF_R(24)
  x0 += k2; x1 += k0 + 2u;
  TF_R(13) TF_R(15) TF_R(26) TF_R(6)
  x0 += k0; x1 += k1 + 3u;
  TF_R(17) TF_R(29) TF_R(16) TF_R(24)
  x0 += k1; x1 += k2 + 4u;
  TF_R(13) TF_R(15) TF_R(26) TF_R(6)
  x0 += k2; x1 += k0 + 5u;
#undef TF_R
  o0 = x0; o1 = x1;
}

// Both keys const-folded (literal inputs), then select by (wave-uniform) h.
__device__ __forceinline__ void derive_key(int which, unsigned& ka, unsigned& kb) {
#if THREEFRY_PARTITIONABLE
  unsigned a0, a1, b0, b1;
  tf2x32(kSeedHi, kSeedLo, 0u, 0u, a0, a1);
  tf2x32(kSeedHi, kSeedLo, 0u, 1u, b0, b1);
  ka = which ? b0 : a0;
  kb = which ? b1 : a1;
#else
  unsigned a0, a1, b0, b1;
  tf2x32(kSeedHi, kSeedLo, 0u, 2u, a0, a1);
  tf2x32(kSeedHi, kSeedLo, 1u, 3u, b0, b1);
  ka = which ? a1 : a0;
  kb = which ? b1 : b0;
#endif
}

__device__ __forceinline__ float bits_to_uniform(unsigned bits) {
  return __uint_as_float((bits >> 9) | 0x3f800000u) - 1.0f;
}

__device__ __forceinline__ float jax_uniform(unsigned ka, unsigned kb, unsigned i) {
#if THREEFRY_PARTITIONABLE
  unsigned o0, o1;
  tf2x32(ka, kb, 0u, i, o0, o1);
  return bits_to_uniform(o0 ^ o1);
#else
  const unsigned H = (unsigned)(kB * kM) / 2u;
  unsigned o0, o1;
  if (i < H) { tf2x32(ka, kb, i, i + H, o0, o1); return bits_to_uniform(o0); }
  else       { tf2x32(ka, kb, i - H, i, o0, o1); return bits_to_uniform(o1); }
#endif
}

// in-mask bin: monotone in value. v in [0x40000000, 0x40400000] (2.0..3.0).
__device__ __forceinline__ unsigned mask_bin(unsigned v) {
  unsigned bn = (v - 0x40000000u) >> 11;
  return bn > 2047u ? 2047u : bn;   // exact-3.0 corner merges into top bin
}

// ---------------------------------------------------------------------------
// Kernel A: 2 threads per roi (gt-half split). Block 256 thr = 128 rois x 2.
// Grid ((kM+127)/128, kB) = (95,16) = 1520 blocks -> ~6 waves/SIMD.
// Inner loop: ONE broadcast ds_read_b128 per gt; area recomputed inline
// (bit-identical f32 expression -> same discrete fg decision as rounds 1-7).
// ---------------------------------------------------------------------------
__global__ __launch_bounds__(256) void k_prep(const float* __restrict__ all_rois,
                                              const float* __restrict__ gt_boxes,
                                              unsigned* __restrict__ vb) {
  __shared__ float4 sg[kG];
  __shared__ int s_fgp[2][128];
  const int b = blockIdx.y;
  const int tid = threadIdx.x;
  if (tid < kG) {
    const float* gp = gt_boxes + ((size_t)b * kG + tid) * 5;
    sg[tid] = make_float4(gp[0], gp[1], gp[2], gp[3]);
  }
  const int rl = tid & 127;          // roi within block
  const int h = tid >> 7;            // gt half 0/1 (wave-uniform)
  const int m = blockIdx.x * 128 + rl;
  const bool valid = (m < kM);
  __syncthreads();

  float bx0 = 0.f, by0 = 0.f, bx1 = 0.f, by1 = 0.f;
  if (valid) {
    if (m < kN) {
      const float* rp = all_rois + ((size_t)b * kN + m) * 5;
      bx0 = rp[1]; by0 = rp[2]; bx1 = rp[3]; by1 = rp[4];
    } else {
      const float4 g4 = sg[m - kN];
      bx0 = g4.x; by0 = g4.y; bx1 = g4.z; by1 = g4.w;
    }
  }
  const float areab = ((bx1 - bx0) + 1.0f) * ((by1 - by0) + 1.0f);

  int fgp = 0;
  const int g0 = h * 64;
#pragma unroll 8
  for (int gg = 0; gg < 64; ++gg) {
    const int g = g0 + gg;
    const float4 g4 = sg[g];
    // inline gt area: identical f32 expression to the old staged sga[g]
    const float ga = ((g4.z - g4.x) + 1.0f) * ((g4.w - g4.y) + 1.0f);
    const float xx0 = fmaxf(bx0, g4.x);
    const float yy0 = fmaxf(by0, g4.y);
    const float xx1 = fminf(bx1, g4.z);
    const float yy1 = fminf(by1, g4.w);
    const float iw = fmaxf((xx1 - xx0) + 1.0f, 0.0f);
    const float ih = fmaxf((yy1 - yy0) + 1.0f, 0.0f);
    const float inter = iw * ih;
    const float denom = (areab + ga) - inter;   // ref op order
    fgp |= (__builtin_fmaf(-0.5f, denom, inter) >= (-0x1p-26f) * denom) ? 1 : 0;
  }
  s_fgp[h][rl] = fgp;
  __syncthreads();
  if (!valid) return;
  const int fg = s_fgp[0][rl] | s_fgp[1][rl];   // exists-g over both halves

  unsigned ka, kb;
  derive_key(h, ka, kb);                        // h wave-uniform select
  const unsigned i = (unsigned)(b * kM + m);
  const float r = jax_uniform(ka, kb, i);
  // h=0: fg channel (r1): +2 iff fg.  h=1: bg channel (r2): +2 iff !fg.
  const float v = (fg ^ h) ? (r + 2.0f) : r;
  vb[(size_t)(h * kB + b) * kM + m] = __float_as_uint(v);
}

// block reduce over nw waves (nw <= 16)
__device__ __forceinline__ int block_reduce_sum_w(int v, int* s_red, int tid, int nw) {
#pragma unroll
  for (int off = 32; off > 0; off >>= 1) v += __shfl_down(v, off, 64);
  __syncthreads();
  if ((tid & 63) == 0) s_red[tid >> 6] = v;
  __syncthreads();
  int t = 0;
  for (int w = 0; w < nw; ++w) t += s_red[w];
  return t;
}

// ---------------------------------------------------------------------------
// Kernel B: one block per (which, b), 1024 threads.
// Histogram on load, scan (first 256 threads) -> threshold bin, filtered
// re-read -> exact rank of ~K+6 candidates.
// ---------------------------------------------------------------------------
__global__ __launch_bounds__(1024) void k_select(const unsigned* __restrict__ vb,
                                                 int* __restrict__ topidx,
                                                 int* __restrict__ nin) {
  __shared__ int s_hist[2048];                  // 8 KB
  __shared__ unsigned long long s_cand[1024];   // 8 KB
  __shared__ int s_scan[256];
  __shared__ int s_red[16];
  __shared__ unsigned long long s_wmax[16];
  __shared__ int s_tbin, s_cnt;

  const int which = blockIdx.x;
  const int b = blockIdx.y;
  const int tid = threadIdx.x;
  const unsigned* src = vb + (size_t)(which * kB + b) * kM;
  const uint4* src4 = (const uint4*)src;
  int* dst = topidx + (size_t)(which * kB + b) * kR;

  for (int i = tid; i < 2048; i += 1024) s_hist[i] = 0;
  if (tid == 0) s_cnt = 0;
  __syncthreads();

  // pass 1: load (L2-hot) + histogram of in-mask values (3 uint4/thread)
  for (int i = tid; i < kM4; i += 1024) {
    const uint4 u = src4[i];
#define HBIN(x) if ((x) >= 0x40000000u) atomicAdd(&s_hist[mask_bin(x)], 1);
    HBIN(u.x) HBIN(u.y) HBIN(u.z) HBIN(u.w)
#undef HBIN
  }
  __syncthreads();

  // chunk sums: first 256 threads own descending 8-bin chunks
  int s = 0;
  if (tid < 256) {
    const int base = 2048 - 8 * (tid + 1);
#pragma unroll
    for (int j = 0; j < 8; ++j) s += s_hist[base + j];
    s_scan[tid] = s;
  }
  const int n_in = block_reduce_sum_w((tid < 256) ? s : 0, s_red, tid, 16);
  if (tid == 0) nin[which * kB + b] = n_in;
  const int quota = (which == 0) ? kFgQuota : kR;
  const int K = imin(n_in, quota);

  if (K == 0) {
    if (which == 0) return;  // fgc==0 -> fg slots never read
    // bg degenerate: reference takes top of UNMASKED r2 -> plain argmax.
    unsigned long long best = 0ull;
    for (int m = tid; m < kM; m += 1024) {
      const unsigned long long key =
          ((unsigned long long)src[m] << 32) | (unsigned)(0xFFFFFFFFu - (unsigned)m);
      if (key > best) best = key;
    }
#pragma unroll
    for (int off = 32; off > 0; off >>= 1) {
      const unsigned long long o = __shfl_down(best, off, 64);
      if (o > best) best = o;
    }
    __syncthreads();
    if ((tid & 63) == 0) s_wmax[tid >> 6] = best;
    __syncthreads();
    if (tid == 0) {
      for (int w = 1; w < 16; ++w) if (s_wmax[w] > best) best = s_wmax[w];
      dst[0] = (int)(0xFFFFFFFFu - (unsigned)(best & 0xFFFFFFFFull));
    }
    return;
  }

  // inclusive scan over the 256 descending chunk sums -> threshold bin
  __syncthreads();
  for (int off = 1; off < 256; off <<= 1) {
    int add = 0;
    if (tid < 256 && tid >= off) add = s_scan[tid - off];
    __syncthreads();
    if (tid < 256) s_scan[tid] += add;
    __syncthreads();
  }
  if (tid < 256) {
    const int base = 2048 - 8 * (tid + 1);
    int s2 = 0;
#pragma unroll
    for (int j = 0; j < 8; ++j) s2 += s_hist[base + j];
    const int above = s_scan[tid] - s2;  // count in bins above my chunk
    int cum = above;
    for (int j = 7; j >= 0; --j) {       // unique crossing: cum < K <= cum+c
      const int c = s_hist[base + j];
      if (cum < K && cum + c >= K) s_tbin = base + j;
      cum += c;
    }
  }
  __syncthreads();
  const unsigned tbin = (unsigned)s_tbin;

  // pass 2: filtered re-read (L2-hot) -> candidates (~K + lambda)
  for (int i = tid; i < kM4; i += 1024) {
    const uint4 u = src4[i];
#define CAND(x, j)                                                         \
    if ((x) >= 0x40000000u && mask_bin(x) >= tbin) {                       \
      const int p = atomicAdd(&s_cnt, 1);                                  \
      if (p < 1024)                                                        \
        s_cand[p] = ((unsigned long long)(x) << 32) |                      \
                    (unsigned)(0xFFFFFFFFu - (unsigned)(4 * i + (j)));     \
    }
    CAND(u.x, 0) CAND(u.y, 1) CAND(u.z, 2) CAND(u.w, 3)
#undef CAND
  }
  __syncthreads();
  const int Nc = imin(s_cnt, 1024);

  // exact rank among candidates (keys pairwise distinct)
  for (int j = tid; j < Nc; j += 1024) {
    const unsigned long long key = s_cand[j];
    int rank = 0;
    for (int i = 0; i < Nc; ++i) rank += (s_cand[i] > key) ? 1 : 0;
    if (rank < K)
      dst[rank] = (int)(0xFFFFFFFFu - (unsigned)(key & 0xFFFFFFFFull));
  }
}

// ---------------------------------------------------------------------------
// Kernel C: one WAVE per output roi (4096 waves, 1024 blocks x 256).
// Lane l handles gt {l, l+64}; butterfly argmax on (iou_bits<<7)|(127-g)
// == reference first-win argmax. Lane 0 writes the 18 outputs.
// ---------------------------------------------------------------------------
__global__ __launch_bounds__(256) void k_final(const float* __restrict__ all_rois,
                                               const float* __restrict__ gt_boxes,
                                               const int* __restrict__ topidx,
                                               const int* __restrict__ nin,
                                               float* __restrict__ out) {
  const int lane = threadIdx.x & 63;
  const int idx = (blockIdx.x << 2) | (threadIdx.x >> 6);  // roi id 0..4095
  const int b = idx >> 8;
  const int pos = idx & 255;

  const int fgc = imin(nin[b], kFgQuota);
  const int bgav = imin(imax(nin[kB + b], 1), kR);
  const bool isfg = pos < fgc;
  int keep;
  if (isfg) keep = topidx[(size_t)b * kR + imin(pos, imax(fgc - 1, 0))];
  else      keep = topidx[(size_t)(kB + b) * kR + (pos - fgc) % bgav];

  const float* bp = (keep < kN) ? (all_rois + ((size_t)b * kN + keep) * 5 + 1)
                                : (gt_boxes + ((size_t)b * kG + (keep - kN)) * 5);
  const float bx0 = bp[0], by0 = bp[1], bx1 = bp[2], by1 = bp[3];
  const float areab = ((bx1 - bx0) + 1.0f) * ((by1 - by0) + 1.0f);

  unsigned long long best = 0ull;
#pragma unroll
  for (int h = 0; h < 2; ++h) {
    const int g = lane + 64 * h;
    const float* gp = gt_boxes + ((size_t)b * kG + g) * 5;
    const float gx0 = gp[0], gy0 = gp[1], gx1 = gp[2], gy1 = gp[3];
    const float ga = ((gx1 - gx0) + 1.0f) * ((gy1 - gy0) + 1.0f);
    const float xx0 = fmaxf(bx0, gx0);
    const float yy0 = fmaxf(by0, gy0);
    const float xx1 = fminf(bx1, gx1);
    const float yy1 = fminf(by1, gy1);
    const float iw = fmaxf((xx1 - xx0) + 1.0f, 0.0f);
    const float ih = fmaxf((yy1 - yy0) + 1.0f, 0.0f);
    const float inter = iw * ih;
    const float iou = inter / ((areab + ga) - inter);   // ref-exact f32 div
    const unsigned long long key =
        ((unsigned long long)__float_as_uint(iou) << 7) | (unsigned)(127 - g);
    if (key > best) best = key;
  }
#pragma unroll
  for (int off = 1; off < 64; off <<= 1) {
    const unsigned long long o = __shfl_xor(best, off, 64);
    if (o > best) best = o;
  }
  const int a = 127 - (int)(best & 127ull);

  const float* gp = gt_boxes + ((size_t)b * kG + a) * 5;
  const float gx0 = gp[0], gy0 = gp[1], gx1 = gp[2], gy1 = gp[3];
  const float lab = isfg ? gp[4] : 0.0f;
  const float fg4 = (lab > 0.0f) ? 1.0f : 0.0f;

  const float ew = (bx1 - bx0) + 1.0f;
  const float eh = (by1 - by0) + 1.0f;
  const float ecx = bx0 + 0.5f * ew;
  const float ecy = by0 + 0.5f * eh;
  const float gw = (gx1 - gx0) + 1.0f;
  const float gh = (gy1 - gy0) + 1.0f;
  const float gcx = gx0 + 0.5f * gw;
  const float gcy = gy0 + 0.5f * gh;
  const float t0 = ((gcx - ecx) / ew) / 0.1f;
  const float t1 = ((gcy - ecy) / eh) / 0.1f;
  const float t2 = logf(gw / ew) / 0.2f;
  const float t3 = logf(gh / eh) / 0.2f;

  if (lane == 0) {
    float* o_rois = out;                                   // [B,R,5]
    float* o_lab  = out + (size_t)kB * kR * 5;             // [B,R]
    float* o_tgt  = o_lab + (size_t)kB * kR;               // [B,R,4]
    float* o_iw   = o_tgt + (size_t)kB * kR * 4;           // [B,R,4]
    float* o_ow   = o_iw  + (size_t)kB * kR * 4;           // [B,R,4]
    const size_t p = (size_t)b * kR + pos;
    o_rois[p * 5 + 0] = (float)b;
    o_rois[p * 5 + 1] = bx0;
    o_rois[p * 5 + 2] = by0;
    o_rois[p * 5 + 3] = bx1;
    o_rois[p * 5 + 4] = by1;
    o_lab[p] = lab;
    o_tgt[p * 4 + 0] = t0 * fg4;
    o_tgt[p * 4 + 1] = t1 * fg4;
    o_tgt[p * 4 + 2] = t2 * fg4;
    o_tgt[p * 4 + 3] = t3 * fg4;
    o_iw[p * 4 + 0] = fg4; o_iw[p * 4 + 1] = fg4;
    o_iw[p * 4 + 2] = fg4; o_iw[p * 4 + 3] = fg4;
    o_ow[p * 4 + 0] = fg4; o_ow[p * 4 + 1] = fg4;
    o_ow[p * 4 + 2] = fg4; o_ow[p * 4 + 3] = fg4;
  }
}

extern "C" void kernel_launch(void* const* d_in, const int* in_sizes, int n_in_args,
                              void* d_out, int out_size, void* d_ws, size_t ws_size,
                              hipStream_t stream) {
  (void)in_sizes; (void)n_in_args; (void)out_size; (void)ws_size;
  const float* all_rois = (const float*)d_in[0];  // [16,12000,5] fp32
  const float* gt_boxes = (const float*)d_in[1];  // [16,128,5] fp32
  float* out = (float*)d_out;

  char* ws = (char*)d_ws;
  unsigned* vb = (unsigned*)ws;                   // 2*kB*kM u32 = 1552384 B
  int* topidx  = (int*)(ws + 1572864);            // 2*kB*kR int = 32 KB
  int* nin     = (int*)(ws + 1572864 + 32768);    // 32 int

  dim3 gA((kM + 127) / 128, kB);                  // (95, 16) = 1520 blocks
  k_prep<<<gA, 256, 0, stream>>>(all_rois, gt_boxes, vb);
  dim3 gB(2, kB);
  k_select<<<gB, 1024, 0, stream>>>(vb, topidx, nin);
  k_final<<<1024, 256, 0, stream>>>(all_rois, gt_boxes, topidx, nin, out);
}